// Round 2
// baseline (156.499 us; speedup 1.0000x reference)
//
#include <hip/hip_runtime.h>
#include <hip/hip_bf16.h>
#include <math.h>

// Weighted-MAE loss: total = sum(w[bin(y)] * |p - y|), count = #valid, out = total/count.
// bin = searchsorted(edge, y, 'right') - 1; valid iff 0 <= bin < n_bins.
// w = weights[largest j with edge[j] <= y]; valid = (y>=edge[0]) && (y<edge[n_bins]).

#define MAXB 8          // bins held in scalar regs (problem has 7); >MAXB falls back to LDS loop
#define NBLOCKS 2048
#define BLOCK 256
#define UNROLL 4

__device__ __forceinline__ float to_sgpr(float x) {
    // edges/weights are wave-uniform: pin them to SGPRs so the select chain
    // costs no VGPRs and cndmask reads them as the one allowed scalar src.
    return __uint_as_float(__builtin_amdgcn_readfirstlane(__float_as_uint(x)));
}

__global__ __launch_bounds__(BLOCK) void wmae_partial(
    const float* __restrict__ y, const float* __restrict__ p,
    const float* __restrict__ weights, const float* __restrict__ edge,
    int n, int n_bins, int n_edges,
    float* __restrict__ psum, float* __restrict__ pcnt)
{
    // generic spillover storage (only read when n_bins > MAXB)
    __shared__ float sh_e[256];
    __shared__ float sh_w[256];
    for (int j = threadIdx.x; j < n_edges && j < 256; j += BLOCK) sh_e[j] = edge[j];
    for (int j = threadIdx.x; j < n_bins  && j < 256; j += BLOCK) sh_w[j] = weights[j];
    __syncthreads();

    // scalar (SGPR) copies for the fast path (compile-time indexed after unroll)
    float ev[MAXB], wv[MAXB];
#pragma unroll
    for (int j = 0; j < MAXB; ++j) {
        ev[j] = to_sgpr((j < n_edges) ? edge[j] : 3.4e38f);
        wv[j] = to_sgpr((j < n_bins)  ? weights[j] : 0.0f);
    }
    const float e0  = ev[0];
    const float eup = to_sgpr((n_bins < n_edges) ? edge[n_bins] : 3.4e38f);

    float sum0 = 0.0f, sum1 = 0.0f;
    int   cnt  = 0;

    auto procA = [&](float yy, float pp) {
        float w = 0.0f;
#pragma unroll
        for (int j = 0; j < MAXB; ++j) if (j < n_bins) w = (yy >= ev[j]) ? wv[j] : w;
        if (n_bins > MAXB)                         // uniform branch; not taken here
            for (int j = MAXB; j < n_bins; ++j) w = (yy >= sh_e[j]) ? sh_w[j] : w;
        bool valid = (yy >= e0) && (yy < eup);
        sum0 += (valid ? w : 0.0f) * fabsf(pp - yy);
        cnt  += valid ? 1 : 0;
    };
    auto procB = [&](float yy, float pp) {
        float w = 0.0f;
#pragma unroll
        for (int j = 0; j < MAXB; ++j) if (j < n_bins) w = (yy >= ev[j]) ? wv[j] : w;
        if (n_bins > MAXB)
            for (int j = MAXB; j < n_bins; ++j) w = (yy >= sh_e[j]) ? sh_w[j] : w;
        bool valid = (yy >= e0) && (yy < eup);
        sum1 += (valid ? w : 0.0f) * fabsf(pp - yy);
        cnt  += valid ? 1 : 0;
    };

    const int tid    = blockIdx.x * BLOCK + threadIdx.x;
    const int stride = gridDim.x * BLOCK;
    const int n4     = n >> 2;
    const float4* y4 = (const float4*)y;
    const float4* p4 = (const float4*)p;

    int i = tid;
    // main unrolled loop: 2*UNROLL float4 loads in flight before any compute
    for (; i + (UNROLL - 1) * stride < n4; i += UNROLL * stride) {
        float4 yv[UNROLL], pv[UNROLL];
#pragma unroll
        for (int u = 0; u < UNROLL; ++u) yv[u] = y4[i + u * stride];
#pragma unroll
        for (int u = 0; u < UNROLL; ++u) pv[u] = p4[i + u * stride];
#pragma unroll
        for (int u = 0; u < UNROLL; ++u) {
            procA(yv[u].x, pv[u].x);
            procB(yv[u].y, pv[u].y);
            procA(yv[u].z, pv[u].z);
            procB(yv[u].w, pv[u].w);
        }
    }
    // remaining strided float4s
    for (; i < n4; i += stride) {
        float4 yv = y4[i];
        float4 pv = p4[i];
        procA(yv.x, pv.x); procB(yv.y, pv.y); procA(yv.z, pv.z); procB(yv.w, pv.w);
    }
    // scalar tail
    for (int k = (n4 << 2) + tid; k < n; k += stride) procA(y[k], p[k]);

    float sum = sum0 + sum1;
    // wave (64-lane) reduce
#pragma unroll
    for (int off = 32; off > 0; off >>= 1) {
        sum += __shfl_down(sum, off, 64);
        cnt += __shfl_down(cnt, off, 64);
    }
    __shared__ float wsum[BLOCK / 64];
    __shared__ int   wcnt[BLOCK / 64];
    const int wave = threadIdx.x >> 6;
    const int lane = threadIdx.x & 63;
    if (lane == 0) { wsum[wave] = sum; wcnt[wave] = cnt; }
    __syncthreads();
    if (threadIdx.x == 0) {
        float s = 0.0f; int c = 0;
#pragma unroll
        for (int w2 = 0; w2 < BLOCK / 64; ++w2) { s += wsum[w2]; c += wcnt[w2]; }
        psum[blockIdx.x] = s;
        pcnt[blockIdx.x] = (float)c;   // counts are integers < 2^24: exact in fp32
    }
}

__global__ __launch_bounds__(BLOCK) void wmae_final(
    const float* __restrict__ psum, const float* __restrict__ pcnt,
    int nparts, float* __restrict__ out)
{
    float s = 0.0f, c = 0.0f;
    for (int i = threadIdx.x; i < nparts; i += BLOCK) { s += psum[i]; c += pcnt[i]; }
#pragma unroll
    for (int off = 32; off > 0; off >>= 1) {
        s += __shfl_down(s, off, 64);
        c += __shfl_down(c, off, 64);
    }
    __shared__ float wsum[BLOCK / 64];
    __shared__ float wcnt[BLOCK / 64];
    const int wave = threadIdx.x >> 6;
    const int lane = threadIdx.x & 63;
    if (lane == 0) { wsum[wave] = s; wcnt[wave] = c; }
    __syncthreads();
    if (threadIdx.x == 0) {
        float S = 0.0f, C = 0.0f;
#pragma unroll
        for (int w2 = 0; w2 < BLOCK / 64; ++w2) { S += wsum[w2]; C += wcnt[w2]; }
        out[0] = S / C;
    }
}

extern "C" void kernel_launch(void* const* d_in, const int* in_sizes, int n_in,
                              void* d_out, int out_size, void* d_ws, size_t ws_size,
                              hipStream_t stream) {
    const float* y       = (const float*)d_in[0];
    const float* p       = (const float*)d_in[1];
    const float* weights = (const float*)d_in[2];
    const float* edge    = (const float*)d_in[3];
    const int n       = in_sizes[0];
    const int n_bins  = in_sizes[2];
    const int n_edges = in_sizes[3];

    float* psum = (float*)d_ws;            // NBLOCKS floats
    float* pcnt = psum + NBLOCKS;          // NBLOCKS floats
    float* out  = (float*)d_out;

    wmae_partial<<<NBLOCKS, BLOCK, 0, stream>>>(y, p, weights, edge,
                                                n, n_bins, n_edges, psum, pcnt);
    wmae_final<<<1, BLOCK, 0, stream>>>(psum, pcnt, NBLOCKS, out);
}

// Round 3
// 151.898 us; speedup vs baseline: 1.0303x; 1.0303x over previous
//
#include <hip/hip_runtime.h>
#include <hip/hip_bf16.h>
#include <math.h>

// Weighted-MAE loss: total = sum(w[bin(y)] * |p - y|), count = #valid, out = total/count.
// bin = searchsorted(edge, y, 'right') - 1; valid iff 0 <= bin < n_bins.
// w = weights[largest j with edge[j] <= y]; valid = (y>=edge[0]) && (y<edge[n_bins]).

#define MAXB 8          // bins held in scalar regs (problem has 7); >MAXB uses generic path
#define NBLOCKS 2048
#define BLOCK 256
#define BATCH 8         // float4-pairs per straight-line batch: 16 loads in flight

__device__ __forceinline__ float to_sgpr(float x) {
    // wave-uniform values pinned to SGPRs: cndmask reads them as the scalar src,
    // costing no VGPRs in the select chain.
    return __uint_as_float(__builtin_amdgcn_readfirstlane(__float_as_uint(x)));
}

// __launch_bounds__(256, 4): 4 waves/SIMD min -> VGPR budget 128. We WANT the
// compiler to spend ~100 VGPRs holding 16 in-flight float4 loads; the default
// (no hint) allocator squeezed to 32 VGPRs and serialized all MLP (R1 lesson).
__global__ __launch_bounds__(BLOCK, 4) void wmae_partial(
    const float* __restrict__ y, const float* __restrict__ p,
    const float* __restrict__ weights, const float* __restrict__ edge,
    int n, int n_bins, int n_edges,
    float* __restrict__ psum, float* __restrict__ pcnt)
{
    // scalar (SGPR) bin tables; ev[j] = +INF for j >= n_bins so the select
    // chain needs NO per-element guard (condition simply never fires).
    float ev[MAXB], wv[MAXB];
#pragma unroll
    for (int j = 0; j < MAXB; ++j) {
        ev[j] = to_sgpr((j < n_bins && j < n_edges) ? edge[j] : 3.4e38f);
        wv[j] = to_sgpr((j < n_bins) ? weights[j] : 0.0f);
    }
    const float e0  = to_sgpr(edge[0]);
    const float eup = to_sgpr((n_bins < n_edges) ? edge[n_bins] : 3.4e38f);

    float sum0 = 0.0f, sum1 = 0.0f;
    int   cnt0 = 0,    cnt1 = 0;

    const int tid    = blockIdx.x * BLOCK + threadIdx.x;
    const int stride = gridDim.x * BLOCK;
    const int n4     = n >> 2;
    const float4* y4 = (const float4*)y;
    const float4* p4 = (const float4*)p;

    if (n_bins <= MAXB) {                     // fast path (uniform branch, taken)
        auto procA = [&](float yy, float pp) {
            float w = 0.0f;
#pragma unroll
            for (int j = 0; j < MAXB; ++j) w = (yy >= ev[j]) ? wv[j] : w;
            bool valid = (yy >= e0) && (yy < eup);
            sum0 += (valid ? w : 0.0f) * fabsf(pp - yy);
            cnt0 += valid ? 1 : 0;
        };
        auto procB = [&](float yy, float pp) {
            float w = 0.0f;
#pragma unroll
            for (int j = 0; j < MAXB; ++j) w = (yy >= ev[j]) ? wv[j] : w;
            bool valid = (yy >= e0) && (yy < eup);
            sum1 += (valid ? w : 0.0f) * fabsf(pp - yy);
            cnt1 += valid ? 1 : 0;
        };

        int i = tid;
        // straight-line batch: 16 independent dwordx4 loads, then compute.
        for (; i + (BATCH - 1) * stride < n4; i += BATCH * stride) {
            float4 yv[BATCH], pv[BATCH];
#pragma unroll
            for (int u = 0; u < BATCH; ++u) yv[u] = y4[i + u * stride];
#pragma unroll
            for (int u = 0; u < BATCH; ++u) pv[u] = p4[i + u * stride];
#pragma unroll
            for (int u = 0; u < BATCH; ++u) {
                procA(yv[u].x, pv[u].x);
                procB(yv[u].y, pv[u].y);
                procA(yv[u].z, pv[u].z);
                procB(yv[u].w, pv[u].w);
            }
        }
        for (; i < n4; i += stride) {         // leftover strided float4s
            float4 yv = y4[i], pv = p4[i];
            procA(yv.x, pv.x); procB(yv.y, pv.y);
            procA(yv.z, pv.z); procB(yv.w, pv.w);
        }
        for (int k = (n4 << 2) + tid; k < n; k += stride)  // scalar tail
            procA(y[k], p[k]);
    } else {                                  // generic path: any n_bins (scalar, slow)
        for (int k = tid; k < n; k += stride) {
            float yy = y[k], pp = p[k];
            float w = 0.0f;
            for (int j = 0; j < n_bins; ++j) w = (yy >= edge[j]) ? weights[j] : w;
            bool valid = (yy >= edge[0]) && (n_bins < n_edges ? (yy < edge[n_bins]) : true);
            sum0 += (valid ? w : 0.0f) * fabsf(pp - yy);
            cnt0 += valid ? 1 : 0;
        }
    }

    float sum = sum0 + sum1;
    int   cnt = cnt0 + cnt1;
    // wave (64-lane) reduce
#pragma unroll
    for (int off = 32; off > 0; off >>= 1) {
        sum += __shfl_down(sum, off, 64);
        cnt += __shfl_down(cnt, off, 64);
    }
    __shared__ float wsum[BLOCK / 64];
    __shared__ int   wcnt[BLOCK / 64];
    const int wave = threadIdx.x >> 6;
    const int lane = threadIdx.x & 63;
    if (lane == 0) { wsum[wave] = sum; wcnt[wave] = cnt; }
    __syncthreads();
    if (threadIdx.x == 0) {
        float s = 0.0f; int c = 0;
#pragma unroll
        for (int w2 = 0; w2 < BLOCK / 64; ++w2) { s += wsum[w2]; c += wcnt[w2]; }
        psum[blockIdx.x] = s;
        pcnt[blockIdx.x] = (float)c;   // counts are integers < 2^24: exact in fp32
    }
}

__global__ __launch_bounds__(BLOCK) void wmae_final(
    const float* __restrict__ psum, const float* __restrict__ pcnt,
    int nparts, float* __restrict__ out)
{
    float s = 0.0f, c = 0.0f;
    for (int i = threadIdx.x; i < nparts; i += BLOCK) { s += psum[i]; c += pcnt[i]; }
#pragma unroll
    for (int off = 32; off > 0; off >>= 1) {
        s += __shfl_down(s, off, 64);
        c += __shfl_down(c, off, 64);
    }
    __shared__ float wsum[BLOCK / 64];
    __shared__ float wcnt[BLOCK / 64];
    const int wave = threadIdx.x >> 6;
    const int lane = threadIdx.x & 63;
    if (lane == 0) { wsum[wave] = s; wcnt[wave] = c; }
    __syncthreads();
    if (threadIdx.x == 0) {
        float S = 0.0f, C = 0.0f;
#pragma unroll
        for (int w2 = 0; w2 < BLOCK / 64; ++w2) { S += wsum[w2]; C += wcnt[w2]; }
        out[0] = S / C;
    }
}

extern "C" void kernel_launch(void* const* d_in, const int* in_sizes, int n_in,
                              void* d_out, int out_size, void* d_ws, size_t ws_size,
                              hipStream_t stream) {
    const float* y       = (const float*)d_in[0];
    const float* p       = (const float*)d_in[1];
    const float* weights = (const float*)d_in[2];
    const float* edge    = (const float*)d_in[3];
    const int n       = in_sizes[0];
    const int n_bins  = in_sizes[2];
    const int n_edges = in_sizes[3];

    float* psum = (float*)d_ws;            // NBLOCKS floats
    float* pcnt = psum + NBLOCKS;          // NBLOCKS floats
    float* out  = (float*)d_out;

    wmae_partial<<<NBLOCKS, BLOCK, 0, stream>>>(y, p, weights, edge,
                                                n, n_bins, n_edges, psum, pcnt);
    wmae_final<<<1, BLOCK, 0, stream>>>(psum, pcnt, NBLOCKS, out);
}

// Round 5
// 151.159 us; speedup vs baseline: 1.0353x; 1.0049x over previous
//
#include <hip/hip_runtime.h>
#include <hip/hip_bf16.h>
#include <math.h>

// Weighted-MAE loss: total = sum(w[bin(y)] * |p - y|), count = #valid, out = total/count.
// bin = searchsorted(edge, y, 'right') - 1; valid iff 0 <= bin < n_bins.
//
// R4 lesson: a standalone volatile "s_waitcnt" asm does NOT order ordinary
// consumers of the loaded registers. The wait must be data-tied ("+v" on every
// loaded reg). With that fixed, we software-pipeline: issue next chunk's 8
// loads, wait vmcnt(8) for the previous chunk, compute — 8KB/wave in flight
// during compute, compiler cannot serialize.

#define MAXB 8          // bins held in SGPRs (problem has 7); >MAXB uses generic path
#define NB   1024       // blocks; 4096 waves; 4 chunks/wave at n=16.7M
#define BLOCK 256

typedef float vf4 __attribute__((ext_vector_type(4)));

__device__ __forceinline__ float to_sgpr(float x) {
    return __uint_as_float(__builtin_amdgcn_readfirstlane(__float_as_uint(x)));
}

// issue 8 independent 16-B loads covering one 4KB chunk of y and of p
#define ISSUE(Y0,Y1,Y2,Y3,P0,P1,P2,P3, YB, PB)                                      \
    asm volatile("global_load_dwordx4 %0, %1, off"             : "=v"(Y0) : "v"(YB)); \
    asm volatile("global_load_dwordx4 %0, %1, off offset:1024" : "=v"(Y1) : "v"(YB)); \
    asm volatile("global_load_dwordx4 %0, %1, off offset:2048" : "=v"(Y2) : "v"(YB)); \
    asm volatile("global_load_dwordx4 %0, %1, off offset:3072" : "=v"(Y3) : "v"(YB)); \
    asm volatile("global_load_dwordx4 %0, %1, off"             : "=v"(P0) : "v"(PB)); \
    asm volatile("global_load_dwordx4 %0, %1, off offset:1024" : "=v"(P1) : "v"(PB)); \
    asm volatile("global_load_dwordx4 %0, %1, off offset:2048" : "=v"(P2) : "v"(PB)); \
    asm volatile("global_load_dwordx4 %0, %1, off offset:3072" : "=v"(P3) : "v"(PB));

// data-tied waitcnt: consumers of these regs CANNOT be hoisted above it
#define WAITN(N, Y0,Y1,Y2,Y3,P0,P1,P2,P3)                                           \
    asm volatile("s_waitcnt vmcnt(" #N ")"                                          \
        : "+v"(Y0), "+v"(Y1), "+v"(Y2), "+v"(Y3),                                   \
          "+v"(P0), "+v"(P1), "+v"(P2), "+v"(P3) :: "memory");

#define COMPUTE(Y0,Y1,Y2,Y3,P0,P1,P2,P3)                                            \
    proc(Y0.x,P0.x); proc(Y0.y,P0.y); proc(Y0.z,P0.z); proc(Y0.w,P0.w);             \
    proc(Y1.x,P1.x); proc(Y1.y,P1.y); proc(Y1.z,P1.z); proc(Y1.w,P1.w);             \
    proc(Y2.x,P2.x); proc(Y2.y,P2.y); proc(Y2.z,P2.z); proc(Y2.w,P2.w);             \
    proc(Y3.x,P3.x); proc(Y3.y,P3.y); proc(Y3.z,P3.z); proc(Y3.w,P3.w);

__global__ __launch_bounds__(BLOCK) void wmae_partial(
    const float* __restrict__ y, const float* __restrict__ p,
    const float* __restrict__ weights, const float* __restrict__ edge,
    int n, int n_bins, int n_edges,
    float* __restrict__ psum, float* __restrict__ pcnt)
{
    // SGPR bin tables; ev[j] = +INF for j >= n_bins -> select chain needs no guard
    float ev[MAXB], wv[MAXB];
#pragma unroll
    for (int j = 0; j < MAXB; ++j) {
        ev[j] = to_sgpr((j < n_bins && j < n_edges) ? edge[j] : 3.4e38f);
        wv[j] = to_sgpr((j < n_bins) ? weights[j] : 0.0f);
    }
    const float e0  = to_sgpr(edge[0]);
    const float eup = to_sgpr((n_bins < n_edges) ? edge[n_bins] : 3.4e38f);

    float sum = 0.0f;
    int   cnt = 0;

    auto proc = [&](float yy, float pp) {
        float w = 0.0f;
#pragma unroll
        for (int j = 0; j < MAXB; ++j) w = (yy >= ev[j]) ? wv[j] : w;
        bool valid = (yy >= e0) && (yy < eup);
        sum += (valid ? w : 0.0f) * fabsf(pp - yy);
        cnt += valid ? 1 : 0;
    };

    const int lane   = threadIdx.x & 63;
    const int wid    = blockIdx.x * (BLOCK / 64) + (threadIdx.x >> 6);
    const int nwaves = gridDim.x * (BLOCK / 64);

    if (n_bins <= MAXB) {
        const int nchunk = n >> 10;          // 1024-float (4KB) chunks
        int c = wid;
        if (c < nchunk) {
            vf4 ya0, ya1, ya2, ya3, pa0, pa1, pa2, pa3;   // buffer A
            vf4 yb0, yb1, yb2, yb3, pb0, pb1, pb2, pb3;   // buffer B
            {
                const float* yb_ = y + ((size_t)c << 10) + lane * 4;
                const float* pb_ = p + ((size_t)c << 10) + lane * 4;
                ISSUE(ya0,ya1,ya2,ya3,pa0,pa1,pa2,pa3, yb_, pb_)
            }
            for (;;) {
                int c2 = c + nwaves;                       // B's chunk
                bool more = (c2 < nchunk);
                if (more) {
                    const float* yb_ = y + ((size_t)c2 << 10) + lane * 4;
                    const float* pb_ = p + ((size_t)c2 << 10) + lane * 4;
                    ISSUE(yb0,yb1,yb2,yb3,pb0,pb1,pb2,pb3, yb_, pb_)
                    WAITN(8, ya0,ya1,ya2,ya3,pa0,pa1,pa2,pa3)
                } else {
                    WAITN(0, ya0,ya1,ya2,ya3,pa0,pa1,pa2,pa3)
                }
                COMPUTE(ya0,ya1,ya2,ya3,pa0,pa1,pa2,pa3)
                if (!more) break;

                int c3 = c2 + nwaves;                      // A's next chunk
                bool more2 = (c3 < nchunk);
                if (more2) {
                    const float* yb_ = y + ((size_t)c3 << 10) + lane * 4;
                    const float* pb_ = p + ((size_t)c3 << 10) + lane * 4;
                    ISSUE(ya0,ya1,ya2,ya3,pa0,pa1,pa2,pa3, yb_, pb_)
                    WAITN(8, yb0,yb1,yb2,yb3,pb0,pb1,pb2,pb3)
                } else {
                    WAITN(0, yb0,yb1,yb2,yb3,pb0,pb1,pb2,pb3)
                }
                COMPUTE(yb0,yb1,yb2,yb3,pb0,pb1,pb2,pb3)
                if (!more2) break;
                c = c3;
            }
        }
        // scalar tail over the last (n % 1024) elements, thread-strided
        const int n1  = nchunk << 10;
        const int tid = blockIdx.x * BLOCK + threadIdx.x;
        for (int k = n1 + tid; k < n; k += gridDim.x * BLOCK) proc(y[k], p[k]);
    } else {
        // generic path: any n_bins (scalar, slow, correct)
        const int tid = blockIdx.x * BLOCK + threadIdx.x;
        for (int k = tid; k < n; k += gridDim.x * BLOCK) {
            float yy = y[k], pp = p[k];
            float w = 0.0f;
            for (int j = 0; j < n_bins; ++j) w = (yy >= edge[j]) ? weights[j] : w;
            bool valid = (yy >= edge[0]) && (n_bins < n_edges ? (yy < edge[n_bins]) : true);
            sum += (valid ? w : 0.0f) * fabsf(pp - yy);
            cnt += valid ? 1 : 0;
        }
    }

    // wave (64-lane) reduce
#pragma unroll
    for (int off = 32; off > 0; off >>= 1) {
        sum += __shfl_down(sum, off, 64);
        cnt += __shfl_down(cnt, off, 64);
    }
    __shared__ float wsum[BLOCK / 64];
    __shared__ int   wcnt[BLOCK / 64];
    const int wave = threadIdx.x >> 6;
    if (lane == 0) { wsum[wave] = sum; wcnt[wave] = cnt; }
    __syncthreads();
    if (threadIdx.x == 0) {
        float s = 0.0f; int c = 0;
#pragma unroll
        for (int w2 = 0; w2 < BLOCK / 64; ++w2) { s += wsum[w2]; c += wcnt[w2]; }
        psum[blockIdx.x] = s;
        pcnt[blockIdx.x] = (float)c;   // counts are integers < 2^24: exact in fp32
    }
}

__global__ __launch_bounds__(BLOCK) void wmae_final(
    const float* __restrict__ psum, const float* __restrict__ pcnt,
    int nparts, float* __restrict__ out)
{
    float s = 0.0f, c = 0.0f;
    for (int i = threadIdx.x; i < nparts; i += BLOCK) { s += psum[i]; c += pcnt[i]; }
#pragma unroll
    for (int off = 32; off > 0; off >>= 1) {
        s += __shfl_down(s, off, 64);
        c += __shfl_down(c, off, 64);
    }
    __shared__ float wsum[BLOCK / 64];
    __shared__ float wcnt[BLOCK / 64];
    const int wave = threadIdx.x >> 6;
    const int lane = threadIdx.x & 63;
    if (lane == 0) { wsum[wave] = s; wcnt[wave] = c; }
    __syncthreads();
    if (threadIdx.x == 0) {
        float S = 0.0f, C = 0.0f;
#pragma unroll
        for (int w2 = 0; w2 < BLOCK / 64; ++w2) { S += wsum[w2]; C += wcnt[w2]; }
        out[0] = S / C;
    }
}

extern "C" void kernel_launch(void* const* d_in, const int* in_sizes, int n_in,
                              void* d_out, int out_size, void* d_ws, size_t ws_size,
                              hipStream_t stream) {
    const float* y       = (const float*)d_in[0];
    const float* p       = (const float*)d_in[1];
    const float* weights = (const float*)d_in[2];
    const float* edge    = (const float*)d_in[3];
    const int n       = in_sizes[0];
    const int n_bins  = in_sizes[2];
    const int n_edges = in_sizes[3];

    float* psum = (float*)d_ws;            // NB floats
    float* pcnt = psum + NB;               // NB floats
    float* out  = (float*)d_out;

    wmae_partial<<<NB, BLOCK, 0, stream>>>(y, p, weights, edge,
                                           n, n_bins, n_edges, psum, pcnt);
    wmae_final<<<1, BLOCK, 0, stream>>>(psum, pcnt, NB, out);
}

// Round 6
// 147.148 us; speedup vs baseline: 1.0635x; 1.0273x over previous
//
#include <hip/hip_runtime.h>
#include <hip/hip_bf16.h>
#include <math.h>

// Weighted-MAE loss: total = sum(w[bin(y)] * |p - y|), count = #valid, out = total/count.
// bin = searchsorted(edge, y, 'right') - 1; valid iff 0 <= bin < n_bins.
//
// R5 lesson: time (45 us) is invariant to per-wave MLP (2 vs 16 in flight),
// grid size, and even memory tier (L3-resident replays with 66KB HBM fetch run
// the SAME 45 us as 66MB ones). Nothing is saturated -> issue-bound at
// (likely DVFS-depressed) clock. Only never-tested lever: per-element VALU
// count. This round: detect the canonical QPE weight table and replace the
// 16-instr cmp/cndmask chain with mul+cvt+min+ldexp (~14 instr/elem total).

#define MAXB 8
#define NB   1024       // 4096 waves; n=16.7M -> exactly 4 chunks of 1024 floats/wave
#define BLOCK 256

typedef float vf4 __attribute__((ext_vector_type(4)));

__device__ __forceinline__ float to_sgpr(float x) {
    return __uint_as_float(__builtin_amdgcn_readfirstlane(__float_as_uint(x)));
}

#define ISSUE(Y0,Y1,Y2,Y3,P0,P1,P2,P3, YB, PB)                                      \
    asm volatile("global_load_dwordx4 %0, %1, off"             : "=v"(Y0) : "v"(YB)); \
    asm volatile("global_load_dwordx4 %0, %1, off offset:1024" : "=v"(Y1) : "v"(YB)); \
    asm volatile("global_load_dwordx4 %0, %1, off offset:2048" : "=v"(Y2) : "v"(YB)); \
    asm volatile("global_load_dwordx4 %0, %1, off offset:3072" : "=v"(Y3) : "v"(YB)); \
    asm volatile("global_load_dwordx4 %0, %1, off"             : "=v"(P0) : "v"(PB)); \
    asm volatile("global_load_dwordx4 %0, %1, off offset:1024" : "=v"(P1) : "v"(PB)); \
    asm volatile("global_load_dwordx4 %0, %1, off offset:2048" : "=v"(P2) : "v"(PB)); \
    asm volatile("global_load_dwordx4 %0, %1, off offset:3072" : "=v"(P3) : "v"(PB));

// data-tied waitcnt (R4 lesson): consumers cannot be hoisted above it
#define WAITN(N, Y0,Y1,Y2,Y3,P0,P1,P2,P3)                                           \
    asm volatile("s_waitcnt vmcnt(" #N ")"                                          \
        : "+v"(Y0), "+v"(Y1), "+v"(Y2), "+v"(Y3),                                   \
          "+v"(P0), "+v"(P1), "+v"(P2), "+v"(P3) :: "memory");

#define COMPUTE(F, Y0,Y1,Y2,Y3,P0,P1,P2,P3)                                         \
    F(Y0.x,P0.x); F(Y0.y,P0.y); F(Y0.z,P0.z); F(Y0.w,P0.w);                         \
    F(Y1.x,P1.x); F(Y1.y,P1.y); F(Y1.z,P1.z); F(Y1.w,P1.w);                         \
    F(Y2.x,P2.x); F(Y2.y,P2.y); F(Y2.z,P2.z); F(Y2.w,P2.w);                         \
    F(Y3.x,P3.x); F(Y3.y,P3.y); F(Y3.z,P3.z); F(Y3.w,P3.w);

// software-pipelined chunk walk; PROC is a lambda(yy, pp)
template <typename F>
__device__ __forceinline__ void pipeline(const float* y, const float* p,
                                         int nchunk, int wid, int nwaves, int lane,
                                         F&& proc)
{
    int c = wid;
    if (c >= nchunk) return;
    vf4 ya0, ya1, ya2, ya3, pa0, pa1, pa2, pa3;
    vf4 yb0, yb1, yb2, yb3, pb0, pb1, pb2, pb3;
    {
        const float* yb_ = y + ((size_t)c << 10) + lane * 4;
        const float* pb_ = p + ((size_t)c << 10) + lane * 4;
        ISSUE(ya0,ya1,ya2,ya3,pa0,pa1,pa2,pa3, yb_, pb_)
    }
    for (;;) {
        int c2 = c + nwaves;
        bool more = (c2 < nchunk);
        if (more) {
            const float* yb_ = y + ((size_t)c2 << 10) + lane * 4;
            const float* pb_ = p + ((size_t)c2 << 10) + lane * 4;
            ISSUE(yb0,yb1,yb2,yb3,pb0,pb1,pb2,pb3, yb_, pb_)
            WAITN(8, ya0,ya1,ya2,ya3,pa0,pa1,pa2,pa3)
        } else {
            WAITN(0, ya0,ya1,ya2,ya3,pa0,pa1,pa2,pa3)
        }
        COMPUTE(proc, ya0,ya1,ya2,ya3,pa0,pa1,pa2,pa3)
        if (!more) break;

        int c3 = c2 + nwaves;
        bool more2 = (c3 < nchunk);
        if (more2) {
            const float* yb_ = y + ((size_t)c3 << 10) + lane * 4;
            const float* pb_ = p + ((size_t)c3 << 10) + lane * 4;
            ISSUE(ya0,ya1,ya2,ya3,pa0,pa1,pa2,pa3, yb_, pb_)
            WAITN(8, yb0,yb1,yb2,yb3,pb0,pb1,pb2,pb3)
        } else {
            WAITN(0, yb0,yb1,yb2,yb3,pb0,pb1,pb2,pb3)
        }
        COMPUTE(proc, yb0,yb1,yb2,yb3,pb0,pb1,pb2,pb3)
        if (!more2) break;
        c = c3;
    }
}

__global__ __launch_bounds__(BLOCK) void wmae_partial(
    const float* __restrict__ y, const float* __restrict__ p,
    const float* __restrict__ weights, const float* __restrict__ edge,
    int n, int n_bins, int n_edges,
    float* __restrict__ psum, float* __restrict__ pcnt)
{
    float sum = 0.0f;
    int   cnt = 0;

    const int lane   = threadIdx.x & 63;
    const int wid    = blockIdx.x * (BLOCK / 64) + (threadIdx.x >> 6);
    const int nwaves = gridDim.x * (BLOCK / 64);
    const int tid    = blockIdx.x * BLOCK + threadIdx.x;

    // ---- detect the canonical radar-QPE table (wave-uniform, once) ----
    bool fast = (n_bins == 7) && (n_edges == 8);
    if (fast) {
        const float ce[8] = {0.0f, 0.1f, 10.0f, 20.0f, 30.0f, 40.0f, 50.0f, 100.0f};
        const float cw[7] = {0.1f, 1.0f, 2.0f, 4.0f, 8.0f, 16.0f, 32.0f};
        for (int j = 0; j < 8; ++j) fast = fast && (edge[j] == ce[j]);
        for (int j = 0; j < 7; ++j) fast = fast && (weights[j] == cw[j]);
    }

    if (fast) {
        // w(y) for y in [10,50): 2^floor(y/10); [0.1,10): 1 = 2^0; [50,100): 32 = 2^5;
        // [0,0.1): 0.1 ; outside [0,100): 0. count = #(w != 0) (weights verified nonzero).
        auto proc = [&](float yy, float pp) {
            float t = yy * 0.1f;
            int   i = (int)t;              // trunc; negative y handled by guard below
            i = min(i, 5);
            float w = ldexpf(1.0f, i);     // v_ldexp_f32
            w = (yy < 0.1f)   ? 0.1f : w;
            w = (yy < 0.0f)   ? 0.0f : w;
            w = (yy >= 100.f) ? 0.0f : w;
            sum += w * fabsf(pp - yy);
            cnt += (w != 0.0f) ? 1 : 0;
        };
        const int nchunk = n >> 10;
        pipeline(y, p, nchunk, wid, nwaves, lane, proc);
        const int n1 = nchunk << 10;
        for (int k = n1 + tid; k < n; k += gridDim.x * BLOCK) proc(y[k], p[k]);
    } else if (n_bins <= MAXB) {
        // SGPR compare/select chain (general small-table path)
        float ev[MAXB], wv[MAXB];
#pragma unroll
        for (int j = 0; j < MAXB; ++j) {
            ev[j] = to_sgpr((j < n_bins && j < n_edges) ? edge[j] : 3.4e38f);
            wv[j] = to_sgpr((j < n_bins) ? weights[j] : 0.0f);
        }
        const float e0  = to_sgpr(edge[0]);
        const float eup = to_sgpr((n_bins < n_edges) ? edge[n_bins] : 3.4e38f);
        auto proc = [&](float yy, float pp) {
            float w = 0.0f;
#pragma unroll
            for (int j = 0; j < MAXB; ++j) w = (yy >= ev[j]) ? wv[j] : w;
            bool valid = (yy >= e0) && (yy < eup);
            sum += (valid ? w : 0.0f) * fabsf(pp - yy);
            cnt += valid ? 1 : 0;
        };
        const int nchunk = n >> 10;
        pipeline(y, p, nchunk, wid, nwaves, lane, proc);
        const int n1 = nchunk << 10;
        for (int k = n1 + tid; k < n; k += gridDim.x * BLOCK) proc(y[k], p[k]);
    } else {
        // fully generic scalar path
        for (int k = tid; k < n; k += gridDim.x * BLOCK) {
            float yy = y[k], pp = p[k];
            float w = 0.0f;
            for (int j = 0; j < n_bins; ++j) w = (yy >= edge[j]) ? weights[j] : w;
            bool valid = (yy >= edge[0]) && (n_bins < n_edges ? (yy < edge[n_bins]) : true);
            sum += (valid ? w : 0.0f) * fabsf(pp - yy);
            cnt += valid ? 1 : 0;
        }
    }

    // wave (64-lane) reduce
#pragma unroll
    for (int off = 32; off > 0; off >>= 1) {
        sum += __shfl_down(sum, off, 64);
        cnt += __shfl_down(cnt, off, 64);
    }
    __shared__ float wsum[BLOCK / 64];
    __shared__ int   wcnt[BLOCK / 64];
    const int wave = threadIdx.x >> 6;
    if (lane == 0) { wsum[wave] = sum; wcnt[wave] = cnt; }
    __syncthreads();
    if (threadIdx.x == 0) {
        float s = 0.0f; int c = 0;
#pragma unroll
        for (int w2 = 0; w2 < BLOCK / 64; ++w2) { s += wsum[w2]; c += wcnt[w2]; }
        psum[blockIdx.x] = s;
        pcnt[blockIdx.x] = (float)c;   // counts are integers < 2^24: exact in fp32
    }
}

__global__ __launch_bounds__(BLOCK) void wmae_final(
    const float* __restrict__ psum, const float* __restrict__ pcnt,
    int nparts, float* __restrict__ out)
{
    float s = 0.0f, c = 0.0f;
    for (int i = threadIdx.x; i < nparts; i += BLOCK) { s += psum[i]; c += pcnt[i]; }
#pragma unroll
    for (int off = 32; off > 0; off >>= 1) {
        s += __shfl_down(s, off, 64);
        c += __shfl_down(c, off, 64);
    }
    __shared__ float wsum[BLOCK / 64];
    __shared__ float wcnt[BLOCK / 64];
    const int wave = threadIdx.x >> 6;
    const int lane = threadIdx.x & 63;
    if (lane == 0) { wsum[wave] = s; wcnt[wave] = c; }
    __syncthreads();
    if (threadIdx.x == 0) {
        float S = 0.0f, C = 0.0f;
#pragma unroll
        for (int w2 = 0; w2 < BLOCK / 64; ++w2) { S += wsum[w2]; C += wcnt[w2]; }
        out[0] = S / C;
    }
}

extern "C" void kernel_launch(void* const* d_in, const int* in_sizes, int n_in,
                              void* d_out, int out_size, void* d_ws, size_t ws_size,
                              hipStream_t stream) {
    const float* y       = (const float*)d_in[0];
    const float* p       = (const float*)d_in[1];
    const float* weights = (const float*)d_in[2];
    const float* edge    = (const float*)d_in[3];
    const int n       = in_sizes[0];
    const int n_bins  = in_sizes[2];
    const int n_edges = in_sizes[3];

    float* psum = (float*)d_ws;            // NB floats
    float* pcnt = psum + NB;               // NB floats
    float* out  = (float*)d_out;

    wmae_partial<<<NB, BLOCK, 0, stream>>>(y, p, weights, edge,
                                           n, n_bins, n_edges, psum, pcnt);
    wmae_final<<<1, BLOCK, 0, stream>>>(psum, pcnt, NB, out);
}